// Round 1
// baseline (1556.173 us; speedup 1.0000x reference)
//
#include <hip/hip_runtime.h>
#include <math.h>

#define NV 196608
#define NDEG 9
#define NC 64
#define NK 8
static constexpr float EPS = 1e-5f;

// ---------------------------------------------------------------------------
// Kernel 1: per-channel sum / sumsq over all V rows (BN batch stats).
// Layout: flat index i = v*64 + c, so channel = i & 63; with blockDim=256 and
// grid stride a multiple of 64, each thread's channel is fixed = tid&63.
// ---------------------------------------------------------------------------
__global__ void __launch_bounds__(256) stats_kernel(const float* __restrict__ x,
                                                    float* __restrict__ stats) {
    int t = blockIdx.x * 256 + threadIdx.x;
    int stride = gridDim.x * 256;
    float s = 0.f, ss = 0.f;
    for (int i = t; i < NV * NC; i += stride) {
        float v = x[i];
        s += v;
        ss += v * v;
    }
    __shared__ float ls[256], lss[256];
    ls[threadIdx.x] = s;
    lss[threadIdx.x] = ss;
    __syncthreads();
    if (threadIdx.x < 64) {
        float a = ls[threadIdx.x] + ls[threadIdx.x + 64] + ls[threadIdx.x + 128] + ls[threadIdx.x + 192];
        float b = lss[threadIdx.x] + lss[threadIdx.x + 64] + lss[threadIdx.x + 128] + lss[threadIdx.x + 192];
        atomicAdd(&stats[threadIdx.x], a);
        atomicAdd(&stats[64 + threadIdx.x], b);
    }
}

__device__ __forceinline__ float mish_f(float h) {
    float sp = (h > 20.f) ? h : log1pf(__expf(h));
    return h * tanhf(sp);
}

// ---------------------------------------------------------------------------
// Kernel 2: BN apply + Mish -> x0 (bufA), and out = bias + x0 @ W[0].
// One wave per row, lane = channel. Row broadcast via __shfl, W0 in LDS.
// ---------------------------------------------------------------------------
__global__ void __launch_bounds__(256) bn_mish_k0(
    const float* __restrict__ x, const float* __restrict__ stats,
    const float* __restrict__ gamma, const float* __restrict__ beta,
    const float* __restrict__ weight, const float* __restrict__ bias,
    float* __restrict__ x0, float* __restrict__ out) {
    __shared__ float Wl[NC * NC];
    for (int i = threadIdx.x; i < NC * NC; i += 256) Wl[i] = weight[i];
    __syncthreads();

    int lane = threadIdx.x & 63;
    int wave = threadIdx.x >> 6;
    float mean = stats[lane] * (1.0f / NV);
    float var  = stats[64 + lane] * (1.0f / NV) - mean * mean;
    float rstd = rsqrtf(var + EPS);
    float scale = gamma[lane] * rstd;
    float shift = beta[lane] - mean * scale;
    float bo = bias[lane];

    int nw = gridDim.x * 4;
    for (int v = blockIdx.x * 4 + wave; v < NV; v += nw) {
        float h = x[v * NC + lane] * scale + shift;
        float m = mish_f(h);
        x0[v * NC + lane] = m;
        float acc = bo;
        #pragma unroll
        for (int i = 0; i < NC; ++i)
            acc += __shfl(m, i) * Wl[i * NC + lane];
        out[v * NC + lane] = acc;
    }
}

// ---------------------------------------------------------------------------
// Kernel 3: one Chebyshev step fused with the einsum accumulation.
//   s = L @ xg              (9 gathers per row, coalesced 256B each)
//   xn = FIRST ? s : 2*s - xw[row]    (xw holds x_{k-2}; overwritten in place)
//   out[row] += xn @ Wk
// One wave per row; (col,val) pairs live in lanes 0..8, broadcast by __shfl.
// ---------------------------------------------------------------------------
template <bool FIRST>
__global__ void __launch_bounds__(256) spmm_cheb(
    const int* __restrict__ cols, const float* __restrict__ vals,
    const float* __restrict__ xg,   // gather source: x_{k-1}
    float* __restrict__ xw,         // x_{k-2} buffer, becomes x_k
    const float* __restrict__ weight,  // &W[k][0][0]
    float* __restrict__ out) {
    __shared__ float Wl[NC * NC];
    for (int i = threadIdx.x; i < NC * NC; i += 256) Wl[i] = weight[i];
    __syncthreads();

    int lane = threadIdx.x & 63;
    int wave = threadIdx.x >> 6;
    int nw = gridDim.x * 4;
    for (int v = blockIdx.x * 4 + wave; v < NV; v += nw) {
        int base = v * NDEG + (lane < NDEG ? lane : NDEG - 1);
        int   colv = cols[base];
        float valv = vals[base];
        float s = 0.f;
        #pragma unroll
        for (int j = 0; j < NDEG; ++j) {
            int   cj = __shfl(colv, j);
            float aj = __shfl(valv, j);
            s += aj * xg[cj * NC + lane];
        }
        float xn;
        if (FIRST) xn = s;
        else       xn = 2.f * s - xw[v * NC + lane];
        xw[v * NC + lane] = xn;

        float acc = out[v * NC + lane];
        #pragma unroll
        for (int i = 0; i < NC; ++i)
            acc += __shfl(xn, i) * Wl[i * NC + lane];
        out[v * NC + lane] = acc;
    }
}

// ---------------------------------------------------------------------------
// Launch: inputs are (x, lap_rows, lap_cols, lap_vals, gamma, beta, weight, bias).
// lap_rows is redundant (row-sorted, exactly 9 nnz per row) and unused.
// ws layout: [0..127] fp32 stats | bufA (V*64 f32) | bufB (V*64 f32)
// ---------------------------------------------------------------------------
extern "C" void kernel_launch(void* const* d_in, const int* in_sizes, int n_in,
                              void* d_out, int out_size, void* d_ws, size_t ws_size,
                              hipStream_t stream) {
    const float* x      = (const float*)d_in[0];
    const int*   cols   = (const int*)  d_in[2];
    const float* vals   = (const float*)d_in[3];
    const float* gamma  = (const float*)d_in[4];
    const float* beta   = (const float*)d_in[5];
    const float* weight = (const float*)d_in[6];
    const float* bias   = (const float*)d_in[7];
    float* out = (float*)d_out;

    float* wsf   = (float*)d_ws;
    float* stats = wsf;
    float* bufA  = wsf + 256;                       // 1 KiB offset, aligned
    float* bufB  = bufA + (size_t)NV * NC;

    hipMemsetAsync(stats, 0, 2 * 64 * sizeof(float), stream);
    stats_kernel<<<1024, 256, 0, stream>>>(x, stats);
    bn_mish_k0<<<2048, 256, 0, stream>>>(x, stats, gamma, beta, weight, bias, bufA, out);

    // k = 1: x1 = L @ x0  (bufA -> bufB), out += x1 @ W1
    spmm_cheb<true><<<2048, 256, 0, stream>>>(cols, vals, bufA, bufB, weight + NC * NC, out);

    // k = 2..7: x_k = 2 L x_{k-1} - x_{k-2}, writing over x_{k-2}'s buffer
    float* cur  = bufB;  // x_{k-1}
    float* prev = bufA;  // x_{k-2}
    for (int k = 2; k < NK; ++k) {
        spmm_cheb<false><<<2048, 256, 0, stream>>>(cols, vals, cur, prev,
                                                   weight + (size_t)k * NC * NC, out);
        float* t = cur; cur = prev; prev = t;
    }
}

// Round 2
// 804.464 us; speedup vs baseline: 1.9344x; 1.9344x over previous
//
#include <hip/hip_runtime.h>
#include <hip/hip_bf16.h>
#include <math.h>

#define NV 196608
#define NDEG 9
#define NC 64
#define NK 8
#define TILE 64
#define NBLK (NV / TILE)   // 3072
#define LDA 72             // padded LDS row stride in bf16 elements (144 B, 16B-aligned)
static constexpr float EPS = 1e-5f;

typedef __attribute__((ext_vector_type(8))) short bf16x8;
typedef __attribute__((ext_vector_type(4))) short bf16x4;
typedef __attribute__((ext_vector_type(4))) float f32x4;

// float -> bf16 bits, round-to-nearest-even (finite inputs)
__device__ __forceinline__ short f2bf(float f) {
    unsigned u = __float_as_uint(f);
    unsigned r = (u + 0x7fffu + ((u >> 16) & 1u)) >> 16;
    return (short)r;
}

// exact mish: h * tanh(softplus(h)); tanh(ln(p)) = (p^2-1)/(p^2+1), p = 1+e^h
__device__ __forceinline__ float mish_f(float h) {
    float t = __expf(fminf(h, 20.f));
    float p = 1.f + t;
    float p2 = p * p;
    return h * ((p2 - 1.f) / (p2 + 1.f));
}

// ---------------------------------------------------------------------------
// Kernel 1: per-channel sum / sumsq (BN batch stats), float4 loads.
// Thread's channel-quad is fixed: c4 = tid & 15 (stride is a multiple of 16).
// ---------------------------------------------------------------------------
__global__ void __launch_bounds__(256) stats_kernel(const float* __restrict__ x,
                                                    float* __restrict__ stats) {
    const float4* x4 = (const float4*)x;
    int t = blockIdx.x * 256 + threadIdx.x;
    int stride = gridDim.x * 256;
    float4 s = {0.f, 0.f, 0.f, 0.f}, ss = {0.f, 0.f, 0.f, 0.f};
    for (int i = t; i < NV * (NC / 4); i += stride) {
        float4 v = x4[i];
        s.x += v.x; s.y += v.y; s.z += v.z; s.w += v.w;
        ss.x += v.x * v.x; ss.y += v.y * v.y; ss.z += v.z * v.z; ss.w += v.w * v.w;
    }
    __shared__ float4 ls[256], lss[256];
    ls[threadIdx.x] = s;
    lss[threadIdx.x] = ss;
    __syncthreads();
    if (threadIdx.x < 64) {
        int ch = threadIdx.x;          // channel 0..63
        int g = ch >> 2, comp = ch & 3;
        float a = 0.f, b = 0.f;
        #pragma unroll
        for (int k = 0; k < 16; ++k) {
            float4 v1 = ls[k * 16 + g];
            float4 v2 = lss[k * 16 + g];
            a += (comp == 0) ? v1.x : (comp == 1) ? v1.y : (comp == 2) ? v1.z : v1.w;
            b += (comp == 0) ? v2.x : (comp == 1) ? v2.y : (comp == 2) ? v2.z : v2.w;
        }
        atomicAdd(&stats[ch], a);
        atomicAdd(&stats[64 + ch], b);
    }
}

// ---------------------------------------------------------------------------
// Kernel 2: BN apply + Mish -> x0 (fp32 global + bf16 LDS tile),
// then out = bias + x0 @ W0 via MFMA. One 64-row tile per block.
// ---------------------------------------------------------------------------
__global__ void __launch_bounds__(256) bn_mish_k0(
    const float* __restrict__ x, const float* __restrict__ stats,
    const float* __restrict__ gamma, const float* __restrict__ beta,
    const float* __restrict__ weight, const float* __restrict__ bias,
    float* __restrict__ x0, float* __restrict__ out) {
    __shared__ short At[TILE * LDA];
    __shared__ short Wt[NC * LDA];
    for (int idx = threadIdx.x; idx < NC * NC; idx += 256) {
        int i = idx >> 6, o = idx & 63;
        Wt[o * LDA + i] = f2bf(weight[idx]);      // W transposed: Wt[o][i]
    }
    __syncthreads();

    int lane = threadIdx.x & 63;
    int wave = threadIdx.x >> 6;
    int rg = lane >> 4;       // row-in-group 0..3
    int c4 = lane & 15;       // float4 column index
    int tile0 = blockIdx.x * TILE;

    // per-channel BN coefficients for this lane's 4 channels
    float4 sc, sh;
    {
        float4 g4 = ((const float4*)gamma)[c4];
        float4 b4 = ((const float4*)beta)[c4];
        #pragma unroll
        for (int q = 0; q < 4; ++q) {
            int ch = 4 * c4 + q;
            float mean = stats[ch] * (1.0f / NV);
            float var = stats[64 + ch] * (1.0f / NV) - mean * mean;
            float rstd = rsqrtf(var + EPS);
            float g = (q == 0) ? g4.x : (q == 1) ? g4.y : (q == 2) ? g4.z : g4.w;
            float b = (q == 0) ? b4.x : (q == 1) ? b4.y : (q == 2) ? b4.z : b4.w;
            float scv = g * rstd;
            float shv = b - mean * scv;
            if (q == 0) { sc.x = scv; sh.x = shv; }
            else if (q == 1) { sc.y = scv; sh.y = shv; }
            else if (q == 2) { sc.z = scv; sh.z = shv; }
            else { sc.w = scv; sh.w = shv; }
        }
    }

    const float4* x4 = (const float4*)x;
    float4* x04 = (float4*)x0;
    #pragma unroll
    for (int it = 0; it < 4; ++it) {
        int rloc = wave * 16 + it * 4 + rg;
        int v = tile0 + rloc;
        float4 h = x4[v * 16 + c4];
        float4 m;
        m.x = mish_f(h.x * sc.x + sh.x);
        m.y = mish_f(h.y * sc.y + sh.y);
        m.z = mish_f(h.z * sc.z + sh.z);
        m.w = mish_f(h.w * sc.w + sh.w);
        x04[v * 16 + c4] = m;
        bf16x4 xb = { f2bf(m.x), f2bf(m.y), f2bf(m.z), f2bf(m.w) };
        *(bf16x4*)&At[rloc * LDA + 4 * c4] = xb;
    }

    // MFMA: each wave multiplies its own 16 rows (no barrier needed)
    int m = lane & 15, q = lane >> 4;
    bf16x8 a0 = *(const bf16x8*)&At[(wave * 16 + m) * LDA + q * 8];
    bf16x8 a1 = *(const bf16x8*)&At[(wave * 16 + m) * LDA + 32 + q * 8];
    #pragma unroll
    for (int nt = 0; nt < 4; ++nt) {
        bf16x8 b0 = *(const bf16x8*)&Wt[(nt * 16 + m) * LDA + q * 8];
        bf16x8 b1 = *(const bf16x8*)&Wt[(nt * 16 + m) * LDA + 32 + q * 8];
        f32x4 acc = {0.f, 0.f, 0.f, 0.f};
        acc = __builtin_amdgcn_mfma_f32_16x16x32_bf16(a0, b0, acc, 0, 0, 0);
        acc = __builtin_amdgcn_mfma_f32_16x16x32_bf16(a1, b1, acc, 0, 0, 0);
        float bcol = bias[nt * 16 + m];
        #pragma unroll
        for (int r = 0; r < 4; ++r) {
            int vout = tile0 + wave * 16 + q * 4 + r;
            out[vout * NC + nt * 16 + m] = bcol + acc[r];
        }
    }
}

// ---------------------------------------------------------------------------
// Kernel 3: one Chebyshev step fused with MFMA einsum accumulation.
//   s = L @ xg (float4 gathers, 4 rows per wave-instruction)
//   xn = FIRST ? s : 2*s - xw[row]  (in-place over x_{k-2})
//   out += xn @ Wk  (bf16 MFMA; recursion itself stays fp32)
// ---------------------------------------------------------------------------
template <bool FIRST>
__global__ void __launch_bounds__(256) spmm_cheb(
    const int* __restrict__ cols, const float* __restrict__ vals,
    const float* __restrict__ xg, float* __restrict__ xw,
    const float* __restrict__ weight, float* __restrict__ out) {
    __shared__ short At[TILE * LDA];
    __shared__ short Wt[NC * LDA];
    for (int idx = threadIdx.x; idx < NC * NC; idx += 256) {
        int i = idx >> 6, o = idx & 63;
        Wt[o * LDA + i] = f2bf(weight[idx]);
    }
    __syncthreads();

    int lane = threadIdx.x & 63;
    int wave = threadIdx.x >> 6;
    int rg = lane >> 4;
    int c4 = lane & 15;
    int tile0 = blockIdx.x * TILE;

    const float4* xg4 = (const float4*)xg;
    float4* xw4 = (float4*)xw;

    #pragma unroll
    for (int it = 0; it < 4; ++it) {
        int rloc = wave * 16 + it * 4 + rg;
        int v = tile0 + rloc;
        const int* cp = cols + v * NDEG;
        const float* vp = vals + v * NDEG;
        float4 s = {0.f, 0.f, 0.f, 0.f};
        #pragma unroll
        for (int j = 0; j < NDEG; ++j) {
            int cj = cp[j];                 // same addr across 16 lanes (L1 broadcast)
            float aj = vp[j];
            float4 g = xg4[cj * 16 + c4];   // 256 B coalesced per row-group
            s.x += aj * g.x; s.y += aj * g.y; s.z += aj * g.z; s.w += aj * g.w;
        }
        float4 xn;
        if (FIRST) {
            xn = s;
        } else {
            float4 p = xw4[v * 16 + c4];
            xn.x = 2.f * s.x - p.x; xn.y = 2.f * s.y - p.y;
            xn.z = 2.f * s.z - p.z; xn.w = 2.f * s.w - p.w;
        }
        xw4[v * 16 + c4] = xn;
        bf16x4 xb = { f2bf(xn.x), f2bf(xn.y), f2bf(xn.z), f2bf(xn.w) };
        *(bf16x4*)&At[rloc * LDA + 4 * c4] = xb;
    }

    // MFMA epilogue: each wave handles its own 16 rows (no barrier needed)
    int m = lane & 15, q = lane >> 4;
    bf16x8 a0 = *(const bf16x8*)&At[(wave * 16 + m) * LDA + q * 8];
    bf16x8 a1 = *(const bf16x8*)&At[(wave * 16 + m) * LDA + 32 + q * 8];
    #pragma unroll
    for (int nt = 0; nt < 4; ++nt) {
        bf16x8 b0 = *(const bf16x8*)&Wt[(nt * 16 + m) * LDA + q * 8];
        bf16x8 b1 = *(const bf16x8*)&Wt[(nt * 16 + m) * LDA + 32 + q * 8];
        f32x4 acc = {0.f, 0.f, 0.f, 0.f};
        acc = __builtin_amdgcn_mfma_f32_16x16x32_bf16(a0, b0, acc, 0, 0, 0);
        acc = __builtin_amdgcn_mfma_f32_16x16x32_bf16(a1, b1, acc, 0, 0, 0);
        #pragma unroll
        for (int r = 0; r < 4; ++r) {
            int vout = tile0 + wave * 16 + q * 4 + r;
            out[vout * NC + nt * 16 + m] += acc[r];
        }
    }
}

// ---------------------------------------------------------------------------
// Launch. Inputs: (x, lap_rows, lap_cols, lap_vals, gamma, beta, weight, bias).
// lap_rows is redundant (row-sorted, exactly 9 nnz/row) and unused.
// ws: [0..255] stats | bufA (V*64 f32) | bufB (V*64 f32)
// ---------------------------------------------------------------------------
extern "C" void kernel_launch(void* const* d_in, const int* in_sizes, int n_in,
                              void* d_out, int out_size, void* d_ws, size_t ws_size,
                              hipStream_t stream) {
    const float* x      = (const float*)d_in[0];
    const int*   cols   = (const int*)  d_in[2];
    const float* vals   = (const float*)d_in[3];
    const float* gamma  = (const float*)d_in[4];
    const float* beta   = (const float*)d_in[5];
    const float* weight = (const float*)d_in[6];
    const float* bias   = (const float*)d_in[7];
    float* out = (float*)d_out;

    float* wsf   = (float*)d_ws;
    float* stats = wsf;
    float* bufA  = wsf + 256;
    float* bufB  = bufA + (size_t)NV * NC;

    hipMemsetAsync(stats, 0, 2 * 64 * sizeof(float), stream);
    stats_kernel<<<1024, 256, 0, stream>>>(x, stats);
    bn_mish_k0<<<NBLK, 256, 0, stream>>>(x, stats, gamma, beta, weight, bias, bufA, out);

    // k = 1: x1 = L @ x0 (bufA -> bufB), out += x1 @ W1
    spmm_cheb<true><<<NBLK, 256, 0, stream>>>(cols, vals, bufA, bufB, weight + NC * NC, out);

    // k = 2..7: x_k = 2 L x_{k-1} - x_{k-2}, overwriting x_{k-2}'s buffer
    float* cur  = bufB;
    float* prev = bufA;
    for (int k = 2; k < NK; ++k) {
        spmm_cheb<false><<<NBLK, 256, 0, stream>>>(cols, vals, cur, prev,
                                                   weight + (size_t)k * NC * NC, out);
        float* t = cur; cur = prev; prev = t;
    }
}